// Round 2
// 15754.355 us; speedup vs baseline: 1.0209x; 1.0209x over previous
//
#include <hip/hip_runtime.h>
#include <hip/hip_bf16.h>

// Persistent dataflow LSTM, 65 WGs (32 L0, 32 L1, 1 head), 1 WG/CU.
// R6 (resubmit; prior round was an infra failure, no kernel verdict):
// L1 merged-gate + fused double-stage (h0+h1 issued together, vmcnt(16)
// split wait; gemm wIH overlaps h1 loads in flight). Single-wave polling.
// x prefetch uses cached (non-sc0sc1) loads so it rides L1/L2, off the
// coherent fabric. L0 hides the x-projection GEMM under h0 stage latency.
// Flags: [0..31] L0post, [32..63] L1pre(stage-done), [64..95] L1post, [96] head.

#define SEQ    2048
#define BATCH  64
#define NIN    256
#define HID    512
#define NWGL   32
#define UPW    16
#define NWG    65
#define NSTEP  (SEQ + 3)

#define RING      65536   // h slot: 64 batch x 512 bf16
#define FLAGS_OFF 0
#define H0_OFF    8192
#define H1_OFF    (H0_OFF + 3 * RING)
// ws use: 8192 + 6*65536 = 401408 bytes

typedef __bf16 bf16x8 __attribute__((ext_vector_type(8)));
typedef float  f32x4  __attribute__((ext_vector_type(4)));
typedef unsigned int u32;
typedef unsigned int u32x4 __attribute__((ext_vector_type(4)));

__device__ __forceinline__ float sigf(float x) { return 1.0f / (1.0f + __expf(-x)); }
__device__ __forceinline__ float tanh_f(float x) { return 2.0f / (1.0f + __expf(-2.0f * x)) - 1.0f; }

__device__ __forceinline__ bf16x8 cvt8(const float* __restrict__ p) {
    bf16x8 r;
#pragma unroll
    for (int i = 0; i < 8; ++i) r[i] = (__bf16)p[i];
    return r;
}

// ---- LLC-coherent (bypass L1/L2) pipelined memory ops ----
__device__ __forceinline__ u32x4 llc_ld16(const void* p) {
    u32x4 r;
    asm volatile("global_load_dwordx4 %0, %1, off sc0 sc1" : "=v"(r) : "v"(p));
    return r;
}
// cached load (read-only data: x input) — stays in L1/L2, still vmcnt-counted
__device__ __forceinline__ u32x4 cached_ld16(const void* p) {
    u32x4 r;
    asm volatile("global_load_dwordx4 %0, %1, off" : "=v"(r) : "v"(p));
    return r;
}
__device__ __forceinline__ void llc_st16(void* p, u32x4 v) {
    asm volatile("global_store_dwordx4 %0, %1, off sc0 sc1" :: "v"(p), "v"(v) : "memory");
}
__device__ __forceinline__ void llc_st4(void* p, u32 v) {
    asm volatile("global_store_dword %0, %1, off sc0 sc1" :: "v"(p), "v"(v) : "memory");
}
__device__ __forceinline__ u32 llc_ld4_wait(const void* p) {
    u32 r;
    asm volatile("global_load_dword %0, %1, off sc0 sc1\n\ts_waitcnt vmcnt(0)"
                 : "=v"(r) : "v"(p) : "memory");
    return r;
}
__device__ __forceinline__ void waitcnt_vm0()  { asm volatile("s_waitcnt vmcnt(0)"  ::: "memory"); }
__device__ __forceinline__ void waitcnt_vm16() { asm volatile("s_waitcnt vmcnt(16)" ::: "memory"); }
__device__ __forceinline__ void waitcnt_vm32() { asm volatile("s_waitcnt vmcnt(32)" ::: "memory"); }

__device__ __forceinline__ void poll_ge(const u32* p, u32 tgt) {
    while (llc_ld4_wait(p) < tgt) __builtin_amdgcn_s_sleep(1);
}

// h-slot staging: LDS chunk layout, piece j=k/8 of batch b -> buf + j*1024 + b*16
__device__ __forceinline__ void stage_issue(const char* __restrict__ slot, int tid, u32x4 (&t)[16]) {
    const int batch = tid >> 2, j0 = tid & 3;
#pragma unroll
    for (int i = 0; i < 16; ++i)
        t[i] = llc_ld16(slot + batch * 1024 + (j0 + 4 * i) * 16);
}
__device__ __forceinline__ void stage_commit(char* __restrict__ buf, int tid, u32x4 (&t)[16]) {
    const int batch = tid >> 2, j0 = tid & 3;
#pragma unroll
    for (int i = 0; i < 16; ++i)
        *(u32x4*)(buf + (j0 + 4 * i) * 1024 + batch * 16) = t[i];
}

__global__ void prep_kernel(char* __restrict__ ws) {
    const int idx = blockIdx.x * blockDim.x + threadIdx.x;
    const int stride = gridDim.x * blockDim.x;
    for (int i = idx; i < 1024 / 4; i += stride)
        llc_st4(ws + FLAGS_OFF + 4 * i, 0u);
    char* s0 = ws + H0_OFF + 2 * RING;   // h[-1] zero slots
    char* s1 = ws + H1_OFF + 2 * RING;
    for (int i = idx; i < RING / 4; i += stride) {
        llc_st4(s0 + 4 * i, 0u);
        llc_st4(s1 + 4 * i, 0u);
    }
}

__global__ void __launch_bounds__(256, 1)
lstm_kernel(const float* __restrict__ xin,
            const float* __restrict__ wih0, const float* __restrict__ whh0,
            const float* __restrict__ bih0, const float* __restrict__ bhh0,
            const float* __restrict__ wih1, const float* __restrict__ whh1,
            const float* __restrict__ bih1, const float* __restrict__ bhh1,
            const float* __restrict__ wout, const float* __restrict__ bout,
            float* __restrict__ out, char* __restrict__ ws)
{
    extern __shared__ char smem[];
    u32*  flags = (u32*)(ws + FLAGS_OFF);
    char* h0r   = ws + H0_OFF;
    char* h1r   = ws + H1_OFF;

    const int wg  = blockIdx.x;
    const int tid = threadIdx.x;
    const int lane = tid & 63;

    if (wg == 64) {
        // ----------------- output head -----------------
        float* wsm  = (float*)smem;
        float* psum = (float*)(smem + 2048);
        for (int i = tid; i < HID; i += 256) wsm[i] = wout[i];
        const float bo = bout[0];
        const int hb = tid >> 2, kq = tid & 3;
        for (int v = 0; v < NSTEP; ++v) {
            if (v >= 3) {
                if (tid < 32) poll_ge(flags + 64 + tid, (u32)v);   // L1 finished step v-1
                __syncthreads();
                const char* hrow = h1r + (size_t)(v % 3) * RING + hb * 1024 + kq * 256;
                u32x4 tv[16];
#pragma unroll
                for (int i = 0; i < 16; ++i) tv[i] = llc_ld16(hrow + i * 16);
                waitcnt_vm0();
                __syncthreads();
                if (tid == 0) llc_st4((void*)(flags + 96), (u32)(v + 1)); // stage done
                const float* wrow = wsm + kq * 128;
                float s = 0.0f;
#pragma unroll
                for (int i = 0; i < 16; ++i) {
                    bf16x8 hv = __builtin_bit_cast(bf16x8, tv[i]);
#pragma unroll
                    for (int e = 0; e < 8; ++e) s += (float)hv[e] * wrow[i * 8 + e];
                }
                psum[tid] = s;
                __syncthreads();
                if (tid < 64) {
                    float d = psum[4 * tid] + psum[4 * tid + 1] + psum[4 * tid + 2] + psum[4 * tid + 3] + bo;
                    out[(size_t)(v - 3) * BATCH + tid] = sigf(d);
                }
                __syncthreads();
            } else {
                if (tid == 0) llc_st4((void*)(flags + 96), (u32)(v + 1));
            }
        }
        return;
    }

    const int layer = wg >> 5;
    const int wgL   = wg & 31;
    const int wave  = tid >> 6;
    const int quad  = lane >> 4;
    const int l16   = lane & 15;
    const int gh    = wave >> 1;
    const int bh    = wave & 1;
    const int bcol0 = 16 * (2 * bh + 0) + l16;
    const int bcol1 = 16 * (2 * bh + 1) + l16;

    char* bufB = smem;
    char* epil = smem;   // [0,2048) reused after GEMM reads complete

    float bias[2][4];
    {
        const float* bi = layer ? bih1 : bih0;
        const float* bb = layer ? bhh1 : bhh0;
#pragma unroll
        for (int t = 0; t < 2; ++t) {
            const int u = wgL * UPW + 4 * (2 * gh + t) + quad;
#pragma unroll
            for (int q = 0; q < 4; ++q) bias[t][q] = bi[q * HID + u] + bb[q * HID + u];
        }
    }
    float cst[2][2] = {{0.f, 0.f}, {0.f, 0.f}};
    f32x4 acc[2][2];

    auto gemm16 = [&](bf16x8 (&W)[2][16]) {
#pragma unroll
        for (int ks = 0; ks < 16; ++ks) {
            bf16x8 B0 = *(const bf16x8*)(bufB + ((ks * 4 + quad) << 10) + (bcol0 << 4));
            bf16x8 B1 = *(const bf16x8*)(bufB + ((ks * 4 + quad) << 10) + (bcol1 << 4));
#pragma unroll
            for (int t = 0; t < 2; ++t) {
                acc[t][0] = __builtin_amdgcn_mfma_f32_16x16x32_bf16(W[t][ks], B0, acc[t][0], 0, 0, 0);
                acc[t][1] = __builtin_amdgcn_mfma_f32_16x16x32_bf16(W[t][ks], B1, acc[t][1], 0, 0, 0);
            }
        }
    };

    auto epilogue = [&](char* wslot, u32* myflag, int v) {
#pragma unroll
        for (int t = 0; t < 2; ++t) {
            const int uloc = 4 * (2 * gh + t) + quad;
#pragma unroll
            for (int b = 0; b < 2; ++b) {
                const float gi = acc[t][b][0] + bias[t][0];
                const float gf = acc[t][b][1] + bias[t][1];
                const float gg = acc[t][b][2] + bias[t][2];
                const float go = acc[t][b][3] + bias[t][3];
                const float cc = sigf(gf) * cst[t][b] + sigf(gi) * tanh_f(gg);
                cst[t][b] = cc;
                const float hh = sigf(go) * tanh_f(cc);
                const int bb = (b == 0) ? bcol0 : bcol1;
                *(unsigned short*)(epil + bb * 32 + uloc * 2) =
                    __builtin_bit_cast(unsigned short, (__bf16)hh);
            }
        }
        __syncthreads();
        if (tid < 128) {
            const int bb = tid >> 1, half = tid & 1;
            u32x4 val = *(const u32x4*)(epil + bb * 32 + half * 16);
            llc_st16(wslot + bb * 1024 + wgL * 32 + half * 16, val);
        }
        waitcnt_vm0();          // per-wave: own data stores ACKed (also drains x prefetch)
        __syncthreads();        // ALL waves drained before flag
        if (tid == 0) llc_st4((void*)myflag, (u32)(v + 1));
    };

    if (layer == 0) {
        // -------- layer 0: x projection hidden under h0 stage latency --------
        bf16x8 wIH[2][8], wHH[2][16];
        {
#pragma unroll
            for (int t = 0; t < 2; ++t) {
                const int r = 16 * (2 * gh + t) + l16;
                const int u = wgL * UPW + (r >> 2);
                const int q = r & 3;
                const float* srcI = wih0 + (size_t)(q * HID + u) * NIN + quad * 8;
                const float* srcH = whh0 + (size_t)(q * HID + u) * HID + quad * 8;
#pragma unroll
                for (int ks = 0; ks < 8; ++ks)  wIH[t][ks] = cvt8(srcI + ks * 32);
#pragma unroll
                for (int ks = 0; ks < 16; ++ks) wHH[t][ks] = cvt8(srcH + ks * 32);
            }
        }
        u32x4 xpre[2][8][2];
        auto issue_x = [&](int xv) {
            const float* xb  = xin + (size_t)xv * BATCH * NIN;
            const float* xr0 = xb + (size_t)bcol0 * NIN + quad * 8;
            const float* xr1 = xb + (size_t)bcol1 * NIN + quad * 8;
#pragma unroll
            for (int ks = 0; ks < 8; ++ks) {
                xpre[0][ks][0] = cached_ld16(xr0 + ks * 32);
                xpre[0][ks][1] = cached_ld16(xr0 + ks * 32 + 4);
                xpre[1][ks][0] = cached_ld16(xr1 + ks * 32);
                xpre[1][ks][1] = cached_ld16(xr1 + ks * 32 + 4);
            }
        };
        issue_x(0);
        waitcnt_vm0();

        for (int v = 0; v < NSTEP; ++v) {
            if (v < SEQ) {
                // gate: peers h0[v-1] published AND L1 done staging h0[v-3]
                if (tid < 64) poll_ge(flags + tid, (u32)v);
                __syncthreads();
#pragma unroll
                for (int t = 0; t < 2; ++t)
#pragma unroll
                    for (int b = 0; b < 2; ++b) acc[t][b] = (f32x4){0.f, 0.f, 0.f, 0.f};
                u32x4 t16[16];
                stage_issue(h0r + (size_t)((v + 2) % 3) * RING, tid, t16);  // h0[v-1]
                // PRE: gates += w_ih0 . x[v] from prefetched regs (hides under stage)
#pragma unroll
                for (int ks = 0; ks < 8; ++ks) {
                    bf16x8 B0, B1;
                    {
                        f32x4 lo = __builtin_bit_cast(f32x4, xpre[0][ks][0]);
                        f32x4 hi = __builtin_bit_cast(f32x4, xpre[0][ks][1]);
#pragma unroll
                        for (int e = 0; e < 4; ++e) { B0[e] = (__bf16)lo[e]; B0[4 + e] = (__bf16)hi[e]; }
                        lo = __builtin_bit_cast(f32x4, xpre[1][ks][0]);
                        hi = __builtin_bit_cast(f32x4, xpre[1][ks][1]);
#pragma unroll
                        for (int e = 0; e < 4; ++e) { B1[e] = (__bf16)lo[e]; B1[4 + e] = (__bf16)hi[e]; }
                    }
#pragma unroll
                    for (int t = 0; t < 2; ++t) {
                        acc[t][0] = __builtin_amdgcn_mfma_f32_16x16x32_bf16(wIH[t][ks], B0, acc[t][0], 0, 0, 0);
                        acc[t][1] = __builtin_amdgcn_mfma_f32_16x16x32_bf16(wIH[t][ks], B1, acc[t][1], 0, 0, 0);
                    }
                }
                issue_x(v + 1 < SEQ ? v + 1 : SEQ - 1);                    // prefetch (dummy on last)
                waitcnt_vm32();                                            // stage loads only
                stage_commit(bufB, tid, t16);
                __syncthreads();
                gemm16(wHH);
                __syncthreads();
                epilogue(h0r + (size_t)(v % 3) * RING, flags + wgL, v);    // h0[v]
            } else {
                if (tid == 0) llc_st4((void*)(flags + wgL), (u32)(v + 1));
            }
        }
    } else {
        // -------- layer 1: merged gate, fused double-stage, wIH gemm overlaps h1 loads --------
        bf16x8 wIH[2][16], wHH[2][16];
        {
#pragma unroll
            for (int t = 0; t < 2; ++t) {
                const int r = 16 * (2 * gh + t) + l16;
                const int u = wgL * UPW + (r >> 2);
                const int q = r & 3;
                const float* srcI = wih1 + (size_t)(q * HID + u) * HID + quad * 8;
                const float* srcH = whh1 + (size_t)(q * HID + u) * HID + quad * 8;
#pragma unroll
                for (int ks = 0; ks < 16; ++ks) { wIH[t][ks] = cvt8(srcI + ks * 32); wHH[t][ks] = cvt8(srcH + ks * 32); }
            }
        }
        for (int v = 0; v < NSTEP; ++v) {
            if (v >= 2 && v < SEQ + 2) {
                // merged gate: L1 peers done v-1 (h1[v-3] ready); L0 done v-2 (h0[v-2]
                // ready); head staged h1[v-5] (slot reuse). Checked in parallel.
                if (tid < 64) {
                    if (lane < 32) poll_ge(flags + 64 + lane, (u32)v);
                    else           poll_ge(flags + (lane - 32), (u32)(v - 1));
                } else if (tid == 64) {
                    poll_ge(flags + 96, (u32)(v - 1));
                }
                __syncthreads();
                u32x4 ta[16], tb[16];
                stage_issue(h0r + (size_t)((v + 1) % 3) * RING, tid, ta);   // h0[v-2]
                stage_issue(h1r + (size_t)(v % 3) * RING, tid, tb);         // h1[v-3]
                waitcnt_vm16();                                             // h0 loads done, h1 in flight
                stage_commit(bufB, tid, ta);
                __syncthreads();
                if (tid == 0) llc_st4((void*)(flags + 32 + wgL), (u32)(v + 1)); // h0 stage done
#pragma unroll
                for (int t = 0; t < 2; ++t)
#pragma unroll
                    for (int b = 0; b < 2; ++b) acc[t][b] = (f32x4){0.f, 0.f, 0.f, 0.f};
                gemm16(wIH);                                                // overlaps h1 loads
                __syncthreads();                                            // all waves done reading h0 tile
                waitcnt_vm0();                                              // h1 loads done
                stage_commit(bufB, tid, tb);
                __syncthreads();
                gemm16(wHH);
                __syncthreads();
                epilogue(h1r + (size_t)((v + 1) % 3) * RING, flags + 64 + wgL, v); // h1[v-2]
            } else {
                if (tid == 0) {
                    llc_st4((void*)(flags + 32 + wgL), (u32)(v + 1));
                    llc_st4((void*)(flags + 64 + wgL), (u32)(v + 1));
                }
            }
        }
    }
}

extern "C" void kernel_launch(void* const* d_in, const int* in_sizes, int n_in,
                              void* d_out, int out_size, void* d_ws, size_t ws_size,
                              hipStream_t stream) {
    (void)in_sizes; (void)n_in; (void)out_size; (void)ws_size;
    const float* xin  = (const float*)d_in[0];
    const float* wih0 = (const float*)d_in[3];
    const float* whh0 = (const float*)d_in[4];
    const float* bih0 = (const float*)d_in[5];
    const float* bhh0 = (const float*)d_in[6];
    const float* wih1 = (const float*)d_in[7];
    const float* whh1 = (const float*)d_in[8];
    const float* bih1 = (const float*)d_in[9];
    const float* bhh1 = (const float*)d_in[10];
    const float* wout = (const float*)d_in[11];
    const float* bout = (const float*)d_in[12];
    float* out = (float*)d_out;
    char* ws = (char*)d_ws;

    hipLaunchKernelGGL(prep_kernel, dim3(64), dim3(256), 0, stream, ws);
    hipLaunchKernelGGL(lstm_kernel, dim3(NWG), dim3(256), 65536, stream,
                       xin, wih0, whh0, bih0, bhh0,
                       wih1, whh1, bih1, bhh1,
                       wout, bout, out, ws);
}

// Round 7
// 15581.229 us; speedup vs baseline: 1.0323x; 1.0111x over previous
//
#include <hip/hip_runtime.h>
#include <hip/hip_bf16.h>

// R11 == byte-identical resubmission of the Round-2-PROVEN kernel (15754 us,
// passed, absmax 0.00390625). Controlled A/B after four consecutive aborts
// with three different kernel bodies: if this aborts too, the environment is
// broken (this exact source passed on this harness); if it passes, the R10
// poll-mechanics delta is the isolated culprit.
// Persistent dataflow LSTM, 65 WGs (32 L0, 32 L1, 1 head), 1 WG/CU.
// L1 merged-gate + fused double-stage (h0+h1 issued together, vmcnt(16)
// split wait; gemm wIH overlaps h1 loads in flight). Single-wave polling.
// x prefetch uses cached (non-sc0sc1) loads so it rides L1/L2, off the
// coherent fabric. L0 hides the x-projection GEMM under h0 stage latency.
// Flags: [0..31] L0post, [32..63] L1pre(stage-done), [64..95] L1post, [96] head.

#define SEQ    2048
#define BATCH  64
#define NIN    256
#define HID    512
#define NWGL   32
#define UPW    16
#define NWG    65
#define NSTEP  (SEQ + 3)

#define RING      65536   // h slot: 64 batch x 512 bf16
#define FLAGS_OFF 0
#define H0_OFF    8192
#define H1_OFF    (H0_OFF + 3 * RING)
// ws use: 8192 + 6*65536 = 401408 bytes

typedef __bf16 bf16x8 __attribute__((ext_vector_type(8)));
typedef float  f32x4  __attribute__((ext_vector_type(4)));
typedef unsigned int u32;
typedef unsigned int u32x4 __attribute__((ext_vector_type(4)));

__device__ __forceinline__ float sigf(float x) { return 1.0f / (1.0f + __expf(-x)); }
__device__ __forceinline__ float tanh_f(float x) { return 2.0f / (1.0f + __expf(-2.0f * x)) - 1.0f; }

__device__ __forceinline__ bf16x8 cvt8(const float* __restrict__ p) {
    bf16x8 r;
#pragma unroll
    for (int i = 0; i < 8; ++i) r[i] = (__bf16)p[i];
    return r;
}

// ---- LLC-coherent (bypass L1/L2) pipelined memory ops ----
__device__ __forceinline__ u32x4 llc_ld16(const void* p) {
    u32x4 r;
    asm volatile("global_load_dwordx4 %0, %1, off sc0 sc1" : "=v"(r) : "v"(p));
    return r;
}
// cached load (read-only data: x input) — stays in L1/L2, still vmcnt-counted
__device__ __forceinline__ u32x4 cached_ld16(const void* p) {
    u32x4 r;
    asm volatile("global_load_dwordx4 %0, %1, off" : "=v"(r) : "v"(p));
    return r;
}
__device__ __forceinline__ void llc_st16(void* p, u32x4 v) {
    asm volatile("global_store_dwordx4 %0, %1, off sc0 sc1" :: "v"(p), "v"(v) : "memory");
}
__device__ __forceinline__ void llc_st4(void* p, u32 v) {
    asm volatile("global_store_dword %0, %1, off sc0 sc1" :: "v"(p), "v"(v) : "memory");
}
__device__ __forceinline__ u32 llc_ld4_wait(const void* p) {
    u32 r;
    asm volatile("global_load_dword %0, %1, off sc0 sc1\n\ts_waitcnt vmcnt(0)"
                 : "=v"(r) : "v"(p) : "memory");
    return r;
}
__device__ __forceinline__ void waitcnt_vm0()  { asm volatile("s_waitcnt vmcnt(0)"  ::: "memory"); }
__device__ __forceinline__ void waitcnt_vm16() { asm volatile("s_waitcnt vmcnt(16)" ::: "memory"); }
__device__ __forceinline__ void waitcnt_vm32() { asm volatile("s_waitcnt vmcnt(32)" ::: "memory"); }

__device__ __forceinline__ void poll_ge(const u32* p, u32 tgt) {
    while (llc_ld4_wait(p) < tgt) __builtin_amdgcn_s_sleep(1);
}

// h-slot staging: LDS chunk layout, piece j=k/8 of batch b -> buf + j*1024 + b*16
__device__ __forceinline__ void stage_issue(const char* __restrict__ slot, int tid, u32x4 (&t)[16]) {
    const int batch = tid >> 2, j0 = tid & 3;
#pragma unroll
    for (int i = 0; i < 16; ++i)
        t[i] = llc_ld16(slot + batch * 1024 + (j0 + 4 * i) * 16);
}
__device__ __forceinline__ void stage_commit(char* __restrict__ buf, int tid, u32x4 (&t)[16]) {
    const int batch = tid >> 2, j0 = tid & 3;
#pragma unroll
    for (int i = 0; i < 16; ++i)
        *(u32x4*)(buf + (j0 + 4 * i) * 1024 + batch * 16) = t[i];
}

__global__ void prep_kernel(char* __restrict__ ws) {
    const int idx = blockIdx.x * blockDim.x + threadIdx.x;
    const int stride = gridDim.x * blockDim.x;
    for (int i = idx; i < 1024 / 4; i += stride)
        llc_st4(ws + FLAGS_OFF + 4 * i, 0u);
    char* s0 = ws + H0_OFF + 2 * RING;   // h[-1] zero slots
    char* s1 = ws + H1_OFF + 2 * RING;
    for (int i = idx; i < RING / 4; i += stride) {
        llc_st4(s0 + 4 * i, 0u);
        llc_st4(s1 + 4 * i, 0u);
    }
}

__global__ void __launch_bounds__(256, 1)
lstm_kernel(const float* __restrict__ xin,
            const float* __restrict__ wih0, const float* __restrict__ whh0,
            const float* __restrict__ bih0, const float* __restrict__ bhh0,
            const float* __restrict__ wih1, const float* __restrict__ whh1,
            const float* __restrict__ bih1, const float* __restrict__ bhh1,
            const float* __restrict__ wout, const float* __restrict__ bout,
            float* __restrict__ out, char* __restrict__ ws)
{
    extern __shared__ char smem[];
    u32*  flags = (u32*)(ws + FLAGS_OFF);
    char* h0r   = ws + H0_OFF;
    char* h1r   = ws + H1_OFF;

    const int wg  = blockIdx.x;
    const int tid = threadIdx.x;
    const int lane = tid & 63;

    if (wg == 64) {
        // ----------------- output head -----------------
        float* wsm  = (float*)smem;
        float* psum = (float*)(smem + 2048);
        for (int i = tid; i < HID; i += 256) wsm[i] = wout[i];
        const float bo = bout[0];
        const int hb = tid >> 2, kq = tid & 3;
        for (int v = 0; v < NSTEP; ++v) {
            if (v >= 3) {
                if (tid < 32) poll_ge(flags + 64 + tid, (u32)v);   // L1 finished step v-1
                __syncthreads();
                const char* hrow = h1r + (size_t)(v % 3) * RING + hb * 1024 + kq * 256;
                u32x4 tv[16];
#pragma unroll
                for (int i = 0; i < 16; ++i) tv[i] = llc_ld16(hrow + i * 16);
                waitcnt_vm0();
                __syncthreads();
                if (tid == 0) llc_st4((void*)(flags + 96), (u32)(v + 1)); // stage done
                const float* wrow = wsm + kq * 128;
                float s = 0.0f;
#pragma unroll
                for (int i = 0; i < 16; ++i) {
                    bf16x8 hv = __builtin_bit_cast(bf16x8, tv[i]);
#pragma unroll
                    for (int e = 0; e < 8; ++e) s += (float)hv[e] * wrow[i * 8 + e];
                }
                psum[tid] = s;
                __syncthreads();
                if (tid < 64) {
                    float d = psum[4 * tid] + psum[4 * tid + 1] + psum[4 * tid + 2] + psum[4 * tid + 3] + bo;
                    out[(size_t)(v - 3) * BATCH + tid] = sigf(d);
                }
                __syncthreads();
            } else {
                if (tid == 0) llc_st4((void*)(flags + 96), (u32)(v + 1));
            }
        }
        return;
    }

    const int layer = wg >> 5;
    const int wgL   = wg & 31;
    const int wave  = tid >> 6;
    const int quad  = lane >> 4;
    const int l16   = lane & 15;
    const int gh    = wave >> 1;
    const int bh    = wave & 1;
    const int bcol0 = 16 * (2 * bh + 0) + l16;
    const int bcol1 = 16 * (2 * bh + 1) + l16;

    char* bufB = smem;
    char* epil = smem;   // [0,2048) reused after GEMM reads complete

    float bias[2][4];
    {
        const float* bi = layer ? bih1 : bih0;
        const float* bb = layer ? bhh1 : bhh0;
#pragma unroll
        for (int t = 0; t < 2; ++t) {
            const int u = wgL * UPW + 4 * (2 * gh + t) + quad;
#pragma unroll
            for (int q = 0; q < 4; ++q) bias[t][q] = bi[q * HID + u] + bb[q * HID + u];
        }
    }
    float cst[2][2] = {{0.f, 0.f}, {0.f, 0.f}};
    f32x4 acc[2][2];

    auto gemm16 = [&](bf16x8 (&W)[2][16]) {
#pragma unroll
        for (int ks = 0; ks < 16; ++ks) {
            bf16x8 B0 = *(const bf16x8*)(bufB + ((ks * 4 + quad) << 10) + (bcol0 << 4));
            bf16x8 B1 = *(const bf16x8*)(bufB + ((ks * 4 + quad) << 10) + (bcol1 << 4));
#pragma unroll
            for (int t = 0; t < 2; ++t) {
                acc[t][0] = __builtin_amdgcn_mfma_f32_16x16x32_bf16(W[t][ks], B0, acc[t][0], 0, 0, 0);
                acc[t][1] = __builtin_amdgcn_mfma_f32_16x16x32_bf16(W[t][ks], B1, acc[t][1], 0, 0, 0);
            }
        }
    };

    auto epilogue = [&](char* wslot, u32* myflag, int v) {
#pragma unroll
        for (int t = 0; t < 2; ++t) {
            const int uloc = 4 * (2 * gh + t) + quad;
#pragma unroll
            for (int b = 0; b < 2; ++b) {
                const float gi = acc[t][b][0] + bias[t][0];
                const float gf = acc[t][b][1] + bias[t][1];
                const float gg = acc[t][b][2] + bias[t][2];
                const float go = acc[t][b][3] + bias[t][3];
                const float cc = sigf(gf) * cst[t][b] + sigf(gi) * tanh_f(gg);
                cst[t][b] = cc;
                const float hh = sigf(go) * tanh_f(cc);
                const int bb = (b == 0) ? bcol0 : bcol1;
                *(unsigned short*)(epil + bb * 32 + uloc * 2) =
                    __builtin_bit_cast(unsigned short, (__bf16)hh);
            }
        }
        __syncthreads();
        if (tid < 128) {
            const int bb = tid >> 1, half = tid & 1;
            u32x4 val = *(const u32x4*)(epil + bb * 32 + half * 16);
            llc_st16(wslot + bb * 1024 + wgL * 32 + half * 16, val);
        }
        waitcnt_vm0();          // per-wave: own data stores ACKed (also drains x prefetch)
        __syncthreads();        // ALL waves drained before flag
        if (tid == 0) llc_st4((void*)myflag, (u32)(v + 1));
    };

    if (layer == 0) {
        // -------- layer 0: x projection hidden under h0 stage latency --------
        bf16x8 wIH[2][8], wHH[2][16];
        {
#pragma unroll
            for (int t = 0; t < 2; ++t) {
                const int r = 16 * (2 * gh + t) + l16;
                const int u = wgL * UPW + (r >> 2);
                const int q = r & 3;
                const float* srcI = wih0 + (size_t)(q * HID + u) * NIN + quad * 8;
                const float* srcH = whh0 + (size_t)(q * HID + u) * HID + quad * 8;
#pragma unroll
                for (int ks = 0; ks < 8; ++ks)  wIH[t][ks] = cvt8(srcI + ks * 32);
#pragma unroll
                for (int ks = 0; ks < 16; ++ks) wHH[t][ks] = cvt8(srcH + ks * 32);
            }
        }
        u32x4 xpre[2][8][2];
        auto issue_x = [&](int xv) {
            const float* xb  = xin + (size_t)xv * BATCH * NIN;
            const float* xr0 = xb + (size_t)bcol0 * NIN + quad * 8;
            const float* xr1 = xb + (size_t)bcol1 * NIN + quad * 8;
#pragma unroll
            for (int ks = 0; ks < 8; ++ks) {
                xpre[0][ks][0] = cached_ld16(xr0 + ks * 32);
                xpre[0][ks][1] = cached_ld16(xr0 + ks * 32 + 4);
                xpre[1][ks][0] = cached_ld16(xr1 + ks * 32);
                xpre[1][ks][1] = cached_ld16(xr1 + ks * 32 + 4);
            }
        };
        issue_x(0);
        waitcnt_vm0();

        for (int v = 0; v < NSTEP; ++v) {
            if (v < SEQ) {
                // gate: peers h0[v-1] published AND L1 done staging h0[v-3]
                if (tid < 64) poll_ge(flags + tid, (u32)v);
                __syncthreads();
#pragma unroll
                for (int t = 0; t < 2; ++t)
#pragma unroll
                    for (int b = 0; b < 2; ++b) acc[t][b] = (f32x4){0.f, 0.f, 0.f, 0.f};
                u32x4 t16[16];
                stage_issue(h0r + (size_t)((v + 2) % 3) * RING, tid, t16);  // h0[v-1]
                // PRE: gates += w_ih0 . x[v] from prefetched regs (hides under stage)
#pragma unroll
                for (int ks = 0; ks < 8; ++ks) {
                    bf16x8 B0, B1;
                    {
                        f32x4 lo = __builtin_bit_cast(f32x4, xpre[0][ks][0]);
                        f32x4 hi = __builtin_bit_cast(f32x4, xpre[0][ks][1]);
#pragma unroll
                        for (int e = 0; e < 4; ++e) { B0[e] = (__bf16)lo[e]; B0[4 + e] = (__bf16)hi[e]; }
                        lo = __builtin_bit_cast(f32x4, xpre[1][ks][0]);
                        hi = __builtin_bit_cast(f32x4, xpre[1][ks][1]);
#pragma unroll
                        for (int e = 0; e < 4; ++e) { B1[e] = (__bf16)lo[e]; B1[4 + e] = (__bf16)hi[e]; }
                    }
#pragma unroll
                    for (int t = 0; t < 2; ++t) {
                        acc[t][0] = __builtin_amdgcn_mfma_f32_16x16x32_bf16(wIH[t][ks], B0, acc[t][0], 0, 0, 0);
                        acc[t][1] = __builtin_amdgcn_mfma_f32_16x16x32_bf16(wIH[t][ks], B1, acc[t][1], 0, 0, 0);
                    }
                }
                issue_x(v + 1 < SEQ ? v + 1 : SEQ - 1);                    // prefetch (dummy on last)
                waitcnt_vm32();                                            // stage loads only
                stage_commit(bufB, tid, t16);
                __syncthreads();
                gemm16(wHH);
                __syncthreads();
                epilogue(h0r + (size_t)(v % 3) * RING, flags + wgL, v);    // h0[v]
            } else {
                if (tid == 0) llc_st4((void*)(flags + wgL), (u32)(v + 1));
            }
        }
    } else {
        // -------- layer 1: merged gate, fused double-stage, wIH gemm overlaps h1 loads --------
        bf16x8 wIH[2][16], wHH[2][16];
        {
#pragma unroll
            for (int t = 0; t < 2; ++t) {
                const int r = 16 * (2 * gh + t) + l16;
                const int u = wgL * UPW + (r >> 2);
                const int q = r & 3;
                const float* srcI = wih1 + (size_t)(q * HID + u) * HID + quad * 8;
                const float* srcH = whh1 + (size_t)(q * HID + u) * HID + quad * 8;
#pragma unroll
                for (int ks = 0; ks < 16; ++ks) { wIH[t][ks] = cvt8(srcI + ks * 32); wHH[t][ks] = cvt8(srcH + ks * 32); }
            }
        }
        for (int v = 0; v < NSTEP; ++v) {
            if (v >= 2 && v < SEQ + 2) {
                // merged gate: L1 peers done v-1 (h1[v-3] ready); L0 done v-2 (h0[v-2]
                // ready); head staged h1[v-5] (slot reuse). Checked in parallel.
                if (tid < 64) {
                    if (lane < 32) poll_ge(flags + 64 + lane, (u32)v);
                    else           poll_ge(flags + (lane - 32), (u32)(v - 1));
                } else if (tid == 64) {
                    poll_ge(flags + 96, (u32)(v - 1));
                }
                __syncthreads();
                u32x4 ta[16], tb[16];
                stage_issue(h0r + (size_t)((v + 1) % 3) * RING, tid, ta);   // h0[v-2]
                stage_issue(h1r + (size_t)(v % 3) * RING, tid, tb);         // h1[v-3]
                waitcnt_vm16();                                             // h0 loads done, h1 in flight
                stage_commit(bufB, tid, ta);
                __syncthreads();
                if (tid == 0) llc_st4((void*)(flags + 32 + wgL), (u32)(v + 1)); // h0 stage done
#pragma unroll
                for (int t = 0; t < 2; ++t)
#pragma unroll
                    for (int b = 0; b < 2; ++b) acc[t][b] = (f32x4){0.f, 0.f, 0.f, 0.f};
                gemm16(wIH);                                                // overlaps h1 loads
                __syncthreads();                                            // all waves done reading h0 tile
                waitcnt_vm0();                                              // h1 loads done
                stage_commit(bufB, tid, tb);
                __syncthreads();
                gemm16(wHH);
                __syncthreads();
                epilogue(h1r + (size_t)((v + 1) % 3) * RING, flags + 64 + wgL, v); // h1[v-2]
            } else {
                if (tid == 0) {
                    llc_st4((void*)(flags + 32 + wgL), (u32)(v + 1));
                    llc_st4((void*)(flags + 64 + wgL), (u32)(v + 1));
                }
            }
        }
    }
}

extern "C" void kernel_launch(void* const* d_in, const int* in_sizes, int n_in,
                              void* d_out, int out_size, void* d_ws, size_t ws_size,
                              hipStream_t stream) {
    (void)in_sizes; (void)n_in; (void)out_size; (void)ws_size;
    const float* xin  = (const float*)d_in[0];
    const float* wih0 = (const float*)d_in[3];
    const float* whh0 = (const float*)d_in[4];
    const float* bih0 = (const float*)d_in[5];
    const float* bhh0 = (const float*)d_in[6];
    const float* wih1 = (const float*)d_in[7];
    const float* whh1 = (const float*)d_in[8];
    const float* bih1 = (const float*)d_in[9];
    const float* bhh1 = (const float*)d_in[10];
    const float* wout = (const float*)d_in[11];
    const float* bout = (const float*)d_in[12];
    float* out = (float*)d_out;
    char* ws = (char*)d_ws;

    hipLaunchKernelGGL(prep_kernel, dim3(64), dim3(256), 0, stream, ws);
    hipLaunchKernelGGL(lstm_kernel, dim3(NWG), dim3(256), 65536, stream,
                       xin, wih0, whh0, bih0, bhh0,
                       wih1, whh1, bih1, bhh1,
                       wout, bout, out, ws);
}